// Round 4
// baseline (1688.010 us; speedup 1.0000x reference)
//
#include <hip/hip_runtime.h>
#include <hip/hip_cooperative_groups.h>

// Problem: bs=8, seq=16, hw=32*32=1024, ck=256, cv=3, steps=seq-1=15
// R9 design: R6 verified math, with the two measured costs attacked:
//  - ONE cooperative launch for all 15 steps (grid.sync between steps):
//    removes 14 kernel boundaries (measured ~4.6us each, R5->R6) and keeps
//    each batch's kh/mkh slice hot in its XCD L2. pv/mv ping-pong traffic is
//    XCD-local (block id%8 = batch). Fallback to per-step launches if coop
//    launch is rejected (attn_span(i,i+1) never executes grid.sync).
//  - software-pipelined A-prefetch (Abuf ping-pong, full unroll) hides L2
//    latency of the 8 A-loads under the previous iteration's MFMA+absorb.
//  - scan_state: 4-elem chunks -> 524288 threads (32 waves/CU) + next-step
//    prefetch: latency-bound 2.4 TB/s -> BW-bound.
#define BS 8
#define SEQ 16
#define HW 1024
#define CK 256
#define CV 3
#define STEPS 15

#define SKP 264   // padded fp16 LDS row stride (256+8)

namespace cg = cooperative_groups;

typedef unsigned short u16;
typedef _Float16 half8 __attribute__((ext_vector_type(8)));  // MFMA A/B frag
typedef float floatx4 __attribute__((ext_vector_type(4)));   // MFMA C/D frag

__device__ __forceinline__ u16 f2h(float f) {
  _Float16 h = (_Float16)f;
  return __builtin_bit_cast(unsigned short, h);
}
__device__ __forceinline__ float h2f(u16 u) {
  _Float16 h = __builtin_bit_cast(_Float16, u);
  return (float)h;
}

// ---- scan_state (once, fully parallel): kh_all = fp16(k[:, i]) for all i,
//      m_kh_all[i] = m_k EMA (fp16 state, fp32 math), pv0 = v[:,0], m_v0 = 0,
//      gt = v[:,1:].  4-elem chunks: 524288 independent chains = 32 waves/CU;
//      next step's k prefetched before the EMA math. ----
__global__ __launch_bounds__(256) void scan_state(
    const float* __restrict__ k, const float* __restrict__ v,
    const float* __restrict__ att,
    u16* __restrict__ kh_all, u16* __restrict__ m_kh_all,
    float* __restrict__ pv0, float* __restrict__ mv0,
    float* __restrict__ out)
{
  long idx = (long)blockIdx.x * 256 + threadIdx.x;
  long stride = (long)gridDim.x * 256;
  const long NCH = (long)BS * HW * 64;         // 524,288 4-elem chunks
  const long SSTR = (long)HW * CK;             // per-step element stride
  for (long t = idx; t < NCH; t += stride) {
    long b = t >> 16;                          // / (HW*64)
    long r = t & 65535;
    long p = r >> 6, s = r & 63;
    const float* kp = k + ((long)b * SEQ * HW + p) * CK + s * 4;
    u16* khp = kh_all + ((long)b * SEQ * HW + p) * CK + s * 4;
    u16* mkp = m_kh_all + ((long)b * STEPS * HW + p) * CK + s * 4;
    const float* ap = att + (long)b * SEQ * HW + p;
    u16 mh[4] = {0, 0, 0, 0};
    float4 nxt = *(const float4*)kp;
    for (int i = 0; i < SEQ; ++i) {
      float4 cur = nxt;
      if (i + 1 < SEQ) nxt = *(const float4*)(kp + (long)(i + 1) * SSTR);
      float kf[4] = {cur.x, cur.y, cur.z, cur.w};
      u16 h4[4];
      #pragma unroll
      for (int j = 0; j < 4; ++j) h4[j] = f2h(kf[j]);
      *(int2*)(khp + (long)i * SSTR) = *(const int2*)h4;
      if (i < STEPS) {
        float a = ap[(long)i * HW];
        float g = 1.0f / (1.0f + __expf(-a)), og = 1.0f - g;
        #pragma unroll
        for (int j = 0; j < 4; ++j)
          mh[j] = f2h(fmaf(g, kf[j], og * h2f(mh[j])));
        *(int2*)(mkp + (long)i * SSTR) = *(const int2*)mh;
      }
    }
  }
  // pv0 = v[:,0], m_v0 = 0
  const long NV = (long)BS * HW * CV;
  for (long t = idx; t < NV; t += stride) {
    long b = t / (HW * CV), r = t - b * (HW * CV);
    pv0[t] = v[(long)b * SEQ * HW * CV + r];
    mv0[t] = 0.0f;
  }
  // gt = v[:,1:]
  const long NG = (long)BS * STEPS * HW * CV;
  for (long t = idx; t < NG; t += stride) {
    long b = t / (STEPS * HW * CV), r = t - b * (STEPS * HW * CV);
    long i = r / (HW * CV), rr = r - i * (HW * CV);
    out[NG + t] = v[((long)b * SEQ + i + 1) * (HW * CV) + rr];
  }
}

// --------- attn_span: steps [s0, s1) in one launch; grid.sync between steps ---
// grid (BS, 32): block = (batch, 32 q-rows), 512 thr = 8 waves, 1 block/CU.
// Per step (verified R6 math): MFMA A = p-rows (streamed, prefetch-pipelined),
// B = q-tile (regs). D[p][q]: lane q-col = lane&15, p-rows = (lane>>4)*4+reg
// -> online softmax over p is in-register. m_v EMA recomputed per block into
// LDS; block y==0 publishes. Cross-block pv/mv exchange via grid.sync (only
// executed when s1-s0 > 1, so the fallback per-step launches are safe).
__global__ __launch_bounds__(512, 2) void attn_span(
    const u16* __restrict__ kh_all, const u16* __restrict__ m_kh_all,
    const float* __restrict__ v, const int* __restrict__ seq_mask,
    const float* __restrict__ att,
    float* __restrict__ mvA, float* __restrict__ mvB,
    float* __restrict__ pvA, float* __restrict__ pvB,
    float* __restrict__ out, int s0, int s1)
{
  __shared__ u16 Kq[32 * SKP];          // q-tile fp16 (16.9 KB)
  __shared__ float Vp[HW * CV];         // prev_v staged (12 KB)
  __shared__ float Vm[HW * CV];         // m_v (updated) staged (12 KB)
  __shared__ float Mg[8][2][32][5];     // per-wave partial states (10.2 KB)

  const int b = blockIdx.x;
  const int q0 = blockIdx.y * 32;
  const int tid = threadIdx.x;
  const int w = tid >> 6, lane = tid & 63;
  const int r = lane & 15, rg = lane >> 4;
  const bool multi = (s1 - s0) > 1;

  for (int step = s0; step < s1; ++step) {
    const float* pv_in  = (step & 1) ? pvB : pvA;
    float*       pv_out = (step & 1) ? pvA : pvB;
    const float* mv_in  = (step & 1) ? mvB : mvA;
    float*       mv_out = (step & 1) ? mvA : mvB;

    const u16* Kn = kh_all + (long)(b * SEQ + step + 1) * HW * CK;  // q side
    const u16* Kc = kh_all + (long)(b * SEQ + step) * HW * CK;      // p side
    const u16* Mb = m_kh_all + (long)(b * STEPS + step) * HW * CK;  // p side

    { // stage q-tile: 1024 16B-chunks over 512 threads
      #pragma unroll
      for (int j = 0; j < 2; ++j) {
        int c = tid + j * 512;
        int row = c >> 5, off = (c & 31) * 8;
        *(int4*)&Kq[row * SKP + off] = *(const int4*)(Kn + (long)(q0 + row) * CK + off);
      }
    }
    { // stage V values + fused m_v EMA: m_v_i = g*pv_i + (1-g)*m_v_{i-1}
      const float* ar = att + (long)(b * SEQ + step) * HW;
      #pragma unroll
      for (int j = 0; j < 2; ++j) {
        int row = tid + j * 512;
        float a = ar[row];
        float g = 1.0f / (1.0f + __expf(-a));
        float og = 1.0f - g;
        long base = (long)(b * HW + row) * CV;
        #pragma unroll
        for (int c = 0; c < CV; ++c) {
          float pv = pv_in[base + c];
          float mv = fmaf(g, pv, og * mv_in[base + c]);
          Vp[row * CV + c] = pv;
          Vm[row * CV + c] = mv;
          if (blockIdx.y == 0) mv_out[base + c] = mv;
        }
      }
    }
    __syncthreads();

    // B fragments (q-tile) held in registers: 2 q-subtiles x 8 k-steps
    half8 Bq[2][8];
    #pragma unroll
    for (int qi = 0; qi < 2; ++qi)
      #pragma unroll
      for (int kk = 0; kk < 8; ++kk)
        Bq[qi][kk] = *(const half8*)&Kq[(qi * 16 + r) * SKP + kk * 32 + rg * 8];

    // online state per (mat, qi)
    float mx[2][2], l[2][2], acc[2][2][3];
    #pragma unroll
    for (int m = 0; m < 2; ++m)
      #pragma unroll
      for (int qi = 0; qi < 2; ++qi) {
        mx[m][qi] = -1e30f; l[m][qi] = 0.f;
        acc[m][qi][0] = acc[m][qi][1] = acc[m][qi][2] = 0.f;
      }

    // flattened iteration it = (pc, mat, pi); A-prefetch ping-pong
    half8 Abuf[2][8];
    { // preload it = 0 (pc=0, mat=0 -> Kc, pi=0)
      const int pr = w * 128;
      #pragma unroll
      for (int kk = 0; kk < 8; ++kk)
        Abuf[0][kk] = *(const half8*)(Kc + (long)(pr + r) * CK + kk * 32 + rg * 8);
    }
    #pragma unroll
    for (int it = 0; it < 16; ++it) {
      const int cur = it & 1;
      if (it + 1 < 16) {  // prefetch next iteration's A fragments
        const int jt = it + 1;
        const int jpc = jt >> 2, jmat = (jt >> 1) & 1, jpi = jt & 1;
        const u16* Abase = jmat ? Mb : Kc;
        const int jpr = w * 128 + jpc * 32 + jpi * 16;
        #pragma unroll
        for (int kk = 0; kk < 8; ++kk)
          Abuf[cur ^ 1][kk] =
              *(const half8*)(Abase + (long)(jpr + r) * CK + kk * 32 + rg * 8);
      }
      const int pc = it >> 2, mat = (it >> 1) & 1, pi = it & 1;
      const int pr = w * 128 + pc * 32 + pi * 16;
      const float* Vb = mat ? Vm : Vp;
      // V values for this lane's 4 p-rows, from LDS (broadcast within rg group)
      float Vv[4][3];
      #pragma unroll
      for (int j = 0; j < 4; ++j) {
        const float* vp = Vb + (pr + rg * 4 + j) * CV;
        Vv[j][0] = vp[0]; Vv[j][1] = vp[1]; Vv[j][2] = vp[2];
      }
      floatx4 c0 = {0.f, 0.f, 0.f, 0.f}, c1 = {0.f, 0.f, 0.f, 0.f};
      #pragma unroll
      for (int kk = 0; kk < 8; ++kk) {
        c0 = __builtin_amdgcn_mfma_f32_16x16x32_f16(Abuf[cur][kk], Bq[0][kk], c0, 0, 0, 0);
        c1 = __builtin_amdgcn_mfma_f32_16x16x32_f16(Abuf[cur][kk], Bq[1][kk], c1, 0, 0, 0);
      }
      #pragma unroll
      for (int qi = 0; qi < 2; ++qi) {
        floatx4 cc = qi ? c1 : c0;
        float tmax = fmaxf(fmaxf(cc[0], cc[1]), fmaxf(cc[2], cc[3]));
        tmax = fmaxf(tmax, mx[mat][qi]);
        float sc = __expf(mx[mat][qi] - tmax);
        l[mat][qi] *= sc;
        acc[mat][qi][0] *= sc; acc[mat][qi][1] *= sc; acc[mat][qi][2] *= sc;
        #pragma unroll
        for (int j = 0; j < 4; ++j) {
          float e = __expf(cc[j] - tmax);
          l[mat][qi] += e;
          acc[mat][qi][0] = fmaf(e, Vv[j][0], acc[mat][qi][0]);
          acc[mat][qi][1] = fmaf(e, Vv[j][1], acc[mat][qi][1]);
          acc[mat][qi][2] = fmaf(e, Vv[j][2], acc[mat][qi][2]);
        }
        mx[mat][qi] = tmax;
      }
    }

    // merge the 4 rowgroup partials (lanes r, r+16, r+32, r+48) via shuffle
    #pragma unroll
    for (int off = 16; off <= 32; off <<= 1) {
      #pragma unroll
      for (int m = 0; m < 2; ++m)
        #pragma unroll
        for (int qi = 0; qi < 2; ++qi) {
          float m2 = __shfl_xor(mx[m][qi], off);
          float l2 = __shfl_xor(l[m][qi], off);
          float b0s = __shfl_xor(acc[m][qi][0], off);
          float b1s = __shfl_xor(acc[m][qi][1], off);
          float b2s = __shfl_xor(acc[m][qi][2], off);
          float mn = fmaxf(mx[m][qi], m2);
          float e1 = __expf(mx[m][qi] - mn), e2 = __expf(m2 - mn);
          l[m][qi] = l[m][qi] * e1 + l2 * e2;
          acc[m][qi][0] = acc[m][qi][0] * e1 + b0s * e2;
          acc[m][qi][1] = acc[m][qi][1] * e1 + b1s * e2;
          acc[m][qi][2] = acc[m][qi][2] * e1 + b2s * e2;
          mx[m][qi] = mn;
        }
    }
    if (rg == 0) {
      #pragma unroll
      for (int m = 0; m < 2; ++m)
        #pragma unroll
        for (int qi = 0; qi < 2; ++qi) {
          float* d = Mg[w][m][qi * 16 + r];
          d[0] = mx[m][qi]; d[1] = l[m][qi];
          d[2] = acc[m][qi][0]; d[3] = acc[m][qi][1]; d[4] = acc[m][qi][2];
        }
    }
    __syncthreads();

    // final cross-wave merge + output: one thread per q-row
    if (tid < 32) {
      const int q = tid;
      float res[2][3];
      #pragma unroll
      for (int m = 0; m < 2; ++m) {
        float M = -1e30f, L = 0.f, A0 = 0.f, A1 = 0.f, A2 = 0.f;
        #pragma unroll
        for (int ww = 0; ww < 8; ++ww) {
          const float* d = Mg[ww][m][q];
          float mn = fmaxf(M, d[0]);
          float e1 = __expf(M - mn), e2 = __expf(d[0] - mn);
          L = L * e1 + d[1] * e2;
          A0 = A0 * e1 + d[2] * e2;
          A1 = A1 * e1 + d[3] * e2;
          A2 = A2 * e1 + d[4] * e2;
          M = mn;
        }
        float iL = 1.0f / L;
        res[m][0] = A0 * iL; res[m][1] = A1 * iL; res[m][2] = A2 * iL;
      }
      const int maskv = seq_mask[b * SEQ + step];
      const int qg = q0 + q;
      float* ov = out + ((long)(b * STEPS + step) * HW + qg) * CV;
      float* po = pv_out + ((long)(b * HW + qg)) * CV;
      const float* vr = v + ((long)(b * SEQ + step) * HW + qg) * CV;
      #pragma unroll
      for (int c = 0; c < CV; ++c) {
        float rec = 0.9f * res[0][c] + 0.1f * res[1][c];  // COEF_MEMORY = 0.1
        ov[c] = rec;
        po[c] = maskv ? vr[c] : rec;
      }
    }

    if (multi) {
      __threadfence();
      cg::this_grid().sync();
    }
  }
}

extern "C" void kernel_launch(void* const* d_in, const int* in_sizes, int n_in,
                              void* d_out, int out_size, void* d_ws, size_t ws_size,
                              hipStream_t stream) {
  const float* k   = (const float*)d_in[0];
  const float* v   = (const float*)d_in[1];
  const float* att = (const float*)d_in[2];
  const int* seq_mask = (const int*)d_in[3];
  float* out = (float*)d_out;
  char* ws = (char*)d_ws;

  // workspace layout (~130.4 MB of the 512 MiB ws):
  // kh_all 67,108,864 | m_kh_all 62,914,560 | pvA,pvB,mvA,mvB 4x98,304
  const size_t KH_ALL  = (size_t)BS * SEQ * HW * CK * 2;
  const size_t MKH_ALL = (size_t)BS * STEPS * HW * CK * 2;
  const size_t SV      = (size_t)BS * HW * CV * 4;

  u16*   kh_all   = (u16*)(ws);
  u16*   m_kh_all = (u16*)(ws + KH_ALL);
  float* pvA      = (float*)(ws + KH_ALL + MKH_ALL);
  float* pvB      = (float*)(ws + KH_ALL + MKH_ALL + SV);
  float* mvA      = (float*)(ws + KH_ALL + MKH_ALL + 2 * SV);
  float* mvB      = (float*)(ws + KH_ALL + MKH_ALL + 3 * SV);

  // all conversions + m_k EMA scan + pv0/mv0 init + gt copy (parallel)
  scan_state<<<2048, 256, 0, stream>>>(k, v, att, kh_all, m_kh_all, pvA, mvA, out);

  // all 15 attention steps in ONE cooperative launch (grid.sync between steps)
  int s0v = 0, s1v = STEPS;
  void* kargs[] = {(void*)&kh_all, (void*)&m_kh_all, (void*)&v, (void*)&seq_mask,
                   (void*)&att, (void*)&mvA, (void*)&mvB, (void*)&pvA, (void*)&pvB,
                   (void*)&out, (void*)&s0v, (void*)&s1v};
  hipError_t ce = hipLaunchCooperativeKernel((void*)attn_span, dim3(BS, 32),
                                             dim3(512, 1, 1), kargs, 0, stream);
  if (ce != hipSuccess) {
    // fallback: per-step launches (grid.sync never executed when s1-s0 == 1)
    for (int i = 0; i < STEPS; ++i)
      attn_span<<<dim3(BS, 32), 512, 0, stream>>>(kh_all, m_kh_all, v, seq_mask,
                                                  att, mvA, mvB, pvA, pvB, out,
                                                  i, i + 1);
  }
}

// Round 5
// 720.286 us; speedup vs baseline: 2.3435x; 2.3435x over previous
//
#include <hip/hip_runtime.h>

// Problem: bs=8, seq=16, hw=32*32=1024, ck=256, cv=3, steps=seq-1=15
// R10 design: exact R6 structure (verified 764us) + spill removal.
//  - attn_step: __launch_bounds__(512,1). R6's (512,2) capped VGPR at 128
//    while body demand is ~150 (Bq 64 + A 32 + state ~50) -> in-loop scratch
//    spills (R9's capped variant: MfmaUtil 3.5%, VALU 6.4%, HBM 0.8% = pure
//    scratch thrash). Cap 256 fits demand with zero spills; occupancy cost
//    (2 blocks/CU -> 1) is the bet.
//  - pc loop unrolled: with register headroom the compiler pipelines the
//    A-loads across subtiles (R9's manual ping-pong goal, no manual cost).
//  - scan_state: 4-elem chunks, 2048 blocks = 8 waves/SIMD TLP (R6's 84us
//    was wave-starved at 2 blocks/CU; R9 verified these numerics).
#define BS 8
#define SEQ 16
#define HW 1024
#define CK 256
#define CV 3
#define STEPS 15

#define SKP 264   // padded fp16 LDS row stride (256+8)

typedef unsigned short u16;
typedef _Float16 half8 __attribute__((ext_vector_type(8)));  // MFMA A/B frag
typedef float floatx4 __attribute__((ext_vector_type(4)));   // MFMA C/D frag

__device__ __forceinline__ u16 f2h(float f) {
  _Float16 h = (_Float16)f;
  return __builtin_bit_cast(unsigned short, h);
}
__device__ __forceinline__ float h2f(u16 u) {
  _Float16 h = __builtin_bit_cast(_Float16, u);
  return (float)h;
}

// ---- scan_state (once, fully parallel): kh_all = fp16(k[:, i]) for all i,
//      m_kh_all[i] = m_k EMA (fp16 state, fp32 math), pv0 = v[:,0], m_v0 = 0,
//      gt = v[:,1:].  4-elem chunks: 524288 chains = 8 waves/SIMD;
//      next step's k prefetched before the EMA math. ----
__global__ __launch_bounds__(256) void scan_state(
    const float* __restrict__ k, const float* __restrict__ v,
    const float* __restrict__ att,
    u16* __restrict__ kh_all, u16* __restrict__ m_kh_all,
    float* __restrict__ pv0, float* __restrict__ mv0,
    float* __restrict__ out)
{
  long idx = (long)blockIdx.x * 256 + threadIdx.x;
  long stride = (long)gridDim.x * 256;
  const long NCH = (long)BS * HW * 64;         // 524,288 4-elem chunks
  const long SSTR = (long)HW * CK;             // per-step element stride
  for (long t = idx; t < NCH; t += stride) {
    long b = t >> 16;                          // / (HW*64)
    long r = t & 65535;
    long p = r >> 6, s = r & 63;
    const float* kp = k + ((long)b * SEQ * HW + p) * CK + s * 4;
    u16* khp = kh_all + ((long)b * SEQ * HW + p) * CK + s * 4;
    u16* mkp = m_kh_all + ((long)b * STEPS * HW + p) * CK + s * 4;
    const float* ap = att + (long)b * SEQ * HW + p;
    u16 mh[4] = {0, 0, 0, 0};
    float4 nxt = *(const float4*)kp;
    for (int i = 0; i < SEQ; ++i) {
      float4 cur = nxt;
      if (i + 1 < SEQ) nxt = *(const float4*)(kp + (long)(i + 1) * SSTR);
      float kf[4] = {cur.x, cur.y, cur.z, cur.w};
      u16 h4[4];
      #pragma unroll
      for (int j = 0; j < 4; ++j) h4[j] = f2h(kf[j]);
      *(int2*)(khp + (long)i * SSTR) = *(const int2*)h4;
      if (i < STEPS) {
        float a = ap[(long)i * HW];
        float g = 1.0f / (1.0f + __expf(-a)), og = 1.0f - g;
        #pragma unroll
        for (int j = 0; j < 4; ++j)
          mh[j] = f2h(fmaf(g, kf[j], og * h2f(mh[j])));
        *(int2*)(mkp + (long)i * SSTR) = *(const int2*)mh;
      }
    }
  }
  // pv0 = v[:,0], m_v0 = 0
  const long NV = (long)BS * HW * CV;
  for (long t = idx; t < NV; t += stride) {
    long b = t / (HW * CV), r = t - b * (HW * CV);
    pv0[t] = v[(long)b * SEQ * HW * CV + r];
    mv0[t] = 0.0f;
  }
  // gt = v[:,1:]
  const long NG = (long)BS * STEPS * HW * CV;
  for (long t = idx; t < NG; t += stride) {
    long b = t / (STEPS * HW * CV), r = t - b * (STEPS * HW * CV);
    long i = r / (HW * CV), rr = r - i * (HW * CV);
    out[NG + t] = v[((long)b * SEQ + i + 1) * (HW * CV) + rr];
  }
}

// --------- per-step fused dual-attention: barrier-free wave-autonomous ---------
// grid (BS, 32): block = (batch, 32 q-rows), 512 thr = 8 waves.
// Wave w owns p-range [w*128, (w+1)*128) as 4 chunks of 32.
// MFMA: A = p-rows (streamed), B = q-tile (regs). D[p][q]: lane q=lane&15,
// p-rows = (lane>>4)*4+reg -> online softmax over p is in-register.
// __launch_bounds__(512,1): VGPR cap 256 -> no spills (demand ~150-200).
__global__ __launch_bounds__(512, 1) void attn_step(
    const u16* __restrict__ kh_all, const u16* __restrict__ m_kh_all,
    const float* __restrict__ v, const int* __restrict__ seq_mask,
    const float* __restrict__ att,
    const float* __restrict__ mv_in, float* __restrict__ mv_out,
    const float* __restrict__ pv_in, float* __restrict__ pv_out,
    float* __restrict__ out, int step)
{
  __shared__ u16 Kq[32 * SKP];          // q-tile fp16 (16.9 KB)
  __shared__ float Vp[HW * CV];         // prev_v staged (12 KB)
  __shared__ float Vm[HW * CV];         // m_v (updated) staged (12 KB)
  __shared__ float Mg[8][2][32][5];     // per-wave partial states (10.2 KB)

  const int b = blockIdx.x;
  const int q0 = blockIdx.y * 32;
  const int tid = threadIdx.x;
  const int w = tid >> 6, lane = tid & 63;
  const int r = lane & 15, rg = lane >> 4;

  const u16* Kn = kh_all + (long)(b * SEQ + step + 1) * HW * CK;  // q side
  const u16* Kc = kh_all + (long)(b * SEQ + step) * HW * CK;      // p side
  const u16* Mb = m_kh_all + (long)(b * STEPS + step) * HW * CK;  // p side

  { // stage q-tile: 1024 16B-chunks over 512 threads
    #pragma unroll
    for (int j = 0; j < 2; ++j) {
      int c = tid + j * 512;
      int row = c >> 5, off = (c & 31) * 8;
      *(int4*)&Kq[row * SKP + off] = *(const int4*)(Kn + (long)(q0 + row) * CK + off);
    }
  }
  { // stage V values + fused m_v EMA: m_v_i = g*pv_i + (1-g)*m_v_{i-1}
    const float* ar = att + (long)(b * SEQ + step) * HW;
    #pragma unroll
    for (int j = 0; j < 2; ++j) {
      int row = tid + j * 512;
      float a = ar[row];
      float g = 1.0f / (1.0f + __expf(-a));
      float og = 1.0f - g;
      long base = (long)(b * HW + row) * CV;
      #pragma unroll
      for (int c = 0; c < CV; ++c) {
        float pv = pv_in[base + c];
        float mv = fmaf(g, pv, og * mv_in[base + c]);
        Vp[row * CV + c] = pv;
        Vm[row * CV + c] = mv;
        if (blockIdx.y == 0) mv_out[base + c] = mv;
      }
    }
  }
  __syncthreads();

  // B fragments (q-tile) held in registers: 2 q-subtiles x 8 k-steps
  half8 Bq[2][8];
  #pragma unroll
  for (int qi = 0; qi < 2; ++qi)
    #pragma unroll
    for (int kk = 0; kk < 8; ++kk)
      Bq[qi][kk] = *(const half8*)&Kq[(qi * 16 + r) * SKP + kk * 32 + rg * 8];

  // online state per (mat, qi): q-col = qi*16 + r, p-subset = this lane's rows
  float mx[2][2], l[2][2], acc[2][2][3];
  #pragma unroll
  for (int m = 0; m < 2; ++m)
    #pragma unroll
    for (int qi = 0; qi < 2; ++qi) {
      mx[m][qi] = -1e30f; l[m][qi] = 0.f;
      acc[m][qi][0] = acc[m][qi][1] = acc[m][qi][2] = 0.f;
    }

  #pragma unroll
  for (int pc = 0; pc < 4; ++pc) {
    const int p0 = w * 128 + pc * 32;
    #pragma unroll
    for (int mat = 0; mat < 2; ++mat) {
      const u16* Ab = mat ? Mb : Kc;
      const float* Vb = mat ? Vm : Vp;
      #pragma unroll
      for (int pi = 0; pi < 2; ++pi) {
        const int pr = p0 + pi * 16;
        // V values for this lane's 4 p-rows, from LDS (broadcast within rg group)
        float Vv[4][3];
        #pragma unroll
        for (int j = 0; j < 4; ++j) {
          const float* vp = Vb + (pr + rg * 4 + j) * CV;
          Vv[j][0] = vp[0]; Vv[j][1] = vp[1]; Vv[j][2] = vp[2];
        }
        // A fragments: 16 p-rows x 32-k per kk step
        half8 A[8];
        #pragma unroll
        for (int kk = 0; kk < 8; ++kk)
          A[kk] = *(const half8*)(Ab + (long)(pr + r) * CK + kk * 32 + rg * 8);
        floatx4 c0 = {0.f, 0.f, 0.f, 0.f}, c1 = {0.f, 0.f, 0.f, 0.f};
        #pragma unroll
        for (int kk = 0; kk < 8; ++kk) {
          c0 = __builtin_amdgcn_mfma_f32_16x16x32_f16(A[kk], Bq[0][kk], c0, 0, 0, 0);
          c1 = __builtin_amdgcn_mfma_f32_16x16x32_f16(A[kk], Bq[1][kk], c1, 0, 0, 0);
        }
        // absorb 4 p-values per qi into online state
        #pragma unroll
        for (int qi = 0; qi < 2; ++qi) {
          floatx4 cc = qi ? c1 : c0;
          float tmax = fmaxf(fmaxf(cc[0], cc[1]), fmaxf(cc[2], cc[3]));
          tmax = fmaxf(tmax, mx[mat][qi]);
          float sc = __expf(mx[mat][qi] - tmax);
          l[mat][qi] *= sc;
          acc[mat][qi][0] *= sc; acc[mat][qi][1] *= sc; acc[mat][qi][2] *= sc;
          #pragma unroll
          for (int j = 0; j < 4; ++j) {
            float e = __expf(cc[j] - tmax);
            l[mat][qi] += e;
            acc[mat][qi][0] = fmaf(e, Vv[j][0], acc[mat][qi][0]);
            acc[mat][qi][1] = fmaf(e, Vv[j][1], acc[mat][qi][1]);
            acc[mat][qi][2] = fmaf(e, Vv[j][2], acc[mat][qi][2]);
          }
          mx[mat][qi] = tmax;
        }
      }
    }
  }

  // merge the 4 rowgroup partials (lanes r, r+16, r+32, r+48) via shuffle
  #pragma unroll
  for (int off = 16; off <= 32; off <<= 1) {
    #pragma unroll
    for (int m = 0; m < 2; ++m)
      #pragma unroll
      for (int qi = 0; qi < 2; ++qi) {
        float m2 = __shfl_xor(mx[m][qi], off);
        float l2 = __shfl_xor(l[m][qi], off);
        float b0s = __shfl_xor(acc[m][qi][0], off);
        float b1s = __shfl_xor(acc[m][qi][1], off);
        float b2s = __shfl_xor(acc[m][qi][2], off);
        float mn = fmaxf(mx[m][qi], m2);
        float e1 = __expf(mx[m][qi] - mn), e2 = __expf(m2 - mn);
        l[m][qi] = l[m][qi] * e1 + l2 * e2;
        acc[m][qi][0] = acc[m][qi][0] * e1 + b0s * e2;
        acc[m][qi][1] = acc[m][qi][1] * e1 + b1s * e2;
        acc[m][qi][2] = acc[m][qi][2] * e1 + b2s * e2;
        mx[m][qi] = mn;
      }
  }
  if (rg == 0) {
    #pragma unroll
    for (int m = 0; m < 2; ++m)
      #pragma unroll
      for (int qi = 0; qi < 2; ++qi) {
        float* d = Mg[w][m][qi * 16 + r];
        d[0] = mx[m][qi]; d[1] = l[m][qi];
        d[2] = acc[m][qi][0]; d[3] = acc[m][qi][1]; d[4] = acc[m][qi][2];
      }
  }
  __syncthreads();

  // final cross-wave merge + output: one thread per q-row
  if (tid < 32) {
    const int q = tid;
    float res[2][3];
    #pragma unroll
    for (int m = 0; m < 2; ++m) {
      float M = -1e30f, L = 0.f, A0 = 0.f, A1 = 0.f, A2 = 0.f;
      #pragma unroll
      for (int ww = 0; ww < 8; ++ww) {
        const float* d = Mg[ww][m][q];
        float mn = fmaxf(M, d[0]);
        float e1 = __expf(M - mn), e2 = __expf(d[0] - mn);
        L = L * e1 + d[1] * e2;
        A0 = A0 * e1 + d[2] * e2;
        A1 = A1 * e1 + d[3] * e2;
        A2 = A2 * e1 + d[4] * e2;
        M = mn;
      }
      float iL = 1.0f / L;
      res[m][0] = A0 * iL; res[m][1] = A1 * iL; res[m][2] = A2 * iL;
    }
    const int maskv = seq_mask[b * SEQ + step];
    const int qg = q0 + q;
    float* ov = out + ((long)(b * STEPS + step) * HW + qg) * CV;
    float* po = pv_out + ((long)(b * HW + qg)) * CV;
    const float* vr = v + ((long)(b * SEQ + step) * HW + qg) * CV;
    #pragma unroll
    for (int c = 0; c < CV; ++c) {
      float rec = 0.9f * res[0][c] + 0.1f * res[1][c];  // COEF_MEMORY = 0.1
      ov[c] = rec;
      po[c] = maskv ? vr[c] : rec;
    }
  }
}

extern "C" void kernel_launch(void* const* d_in, const int* in_sizes, int n_in,
                              void* d_out, int out_size, void* d_ws, size_t ws_size,
                              hipStream_t stream) {
  const float* k   = (const float*)d_in[0];
  const float* v   = (const float*)d_in[1];
  const float* att = (const float*)d_in[2];
  const int* seq_mask = (const int*)d_in[3];
  float* out = (float*)d_out;
  char* ws = (char*)d_ws;

  // workspace layout (~130.4 MB of the 512 MiB ws):
  // kh_all 67,108,864 | m_kh_all 62,914,560 | pvA,pvB,mvA,mvB 4x98,304
  const size_t KH_ALL  = (size_t)BS * SEQ * HW * CK * 2;
  const size_t MKH_ALL = (size_t)BS * STEPS * HW * CK * 2;
  const size_t SV      = (size_t)BS * HW * CV * 4;

  u16*   kh_all   = (u16*)(ws);
  u16*   m_kh_all = (u16*)(ws + KH_ALL);
  float* pvA      = (float*)(ws + KH_ALL + MKH_ALL);
  float* pvB      = (float*)(ws + KH_ALL + MKH_ALL + SV);
  float* mvA      = (float*)(ws + KH_ALL + MKH_ALL + 2 * SV);
  float* mvB      = (float*)(ws + KH_ALL + MKH_ALL + 3 * SV);

  // one parallel kernel: all conversions + m_k scan + pv0/mv0 init + gt copy
  scan_state<<<2048, 256, 0, stream>>>(k, v, att, kh_all, m_kh_all, pvA, mvA, out);

  // serial chain: 15 attention steps only
  for (int i = 0; i < STEPS; ++i) {
    float* pin  = (i & 1) ? pvB : pvA;
    float* pout = (i & 1) ? pvA : pvB;
    float* mvi  = (i & 1) ? mvB : mvA;
    float* mvo  = (i & 1) ? mvA : mvB;
    attn_step<<<dim3(BS, 32), 512, 0, stream>>>(kh_all, m_kh_all, v, seq_mask,
                                                att, mvi, mvo, pin, pout, out, i);
  }
}